// Round 3
// baseline (431.556 us; speedup 1.0000x reference)
//
#include <hip/hip_runtime.h>
#include <hip/hip_bf16.h>

// Problem constants (from reference): B,Q,C,P,A = 32,300,81,300,29
#define BB 32
#define QQ 300
#define CC 81
#define PP 300
#define AA 29

// Flat output layout (fp32 elements), concatenated in reference return order:
// scores(B,Q) | labels(B,Q) | boxes(B,Q,4) | score(B,A,Q,Q+1) | h_mask(B,Q) | o_mask(B,Q+1)
constexpr long long OFF_SCORES = 0;
constexpr long long OFF_LABELS = OFF_SCORES + (long long)BB * QQ;            // 9600
constexpr long long OFF_BOXES  = OFF_LABELS + (long long)BB * QQ;            // 19200
constexpr long long OFF_SCORE  = OFF_BOXES  + (long long)BB * QQ * 4;        // 57600
constexpr long long SCORE_ELEMS = (long long)BB * AA * QQ * (QQ + 1);        // 83,798,400
constexpr long long OFF_HMASK  = OFF_SCORE + SCORE_ELEMS;                    // 83,856,000
constexpr long long OFF_OMASK  = OFF_HMASK + (long long)BB * QQ;             // 83,865,600
// total = 83,875,232 elements

constexpr int SLOTS = QQ * (QQ + 1);          // 90,300 slots per (b,a) plane
constexpr int SLOT4 = SLOTS / 4;              // 22,575 float4 per plane (exact)
constexpr int CHUNKS = (SLOT4 + 1023) / 1024; // 23 chunks of 1024 float4
constexpr size_t LUT_BYTES = (size_t)BB * SLOTS * sizeof(int);  // 11.56 MB

typedef float f32x4 __attribute__((ext_vector_type(4)));

// ---------------------------------------------------------------------------
// Kernel 1a: wide grid-stride init of the LUT to -1 (11.5 MB, ~5 us).
__global__ __launch_bounds__(256) void lut_init_kernel(int* __restrict__ lut) {
    int4* p = (int4*)lut;
    const int n4 = BB * SLOTS / 4;   // 722,400
    int i = blockIdx.x * blockDim.x + threadIdx.x;
    const int stride = gridDim.x * blockDim.x;
    int4 m1 = make_int4(-1, -1, -1, -1);
    for (; i < n4; i += stride) p[i] = m1;
}

// Kernel 1b: scatter pair index p into lut[b, h*(Q+1)+o'] via atomicMax
// (larger p = later pair = numpy last-wins). Auto-detects int64 vs int32
// pred_rel_pairs (values < 300 => int64 little-endian odd words are zero).
__global__ __launch_bounds__(320) void lut_scatter_kernel(const int* __restrict__ pairs,
                                                          int* __restrict__ lut) {
    __shared__ int nz;
    int tid = threadIdx.x;
    int b = blockIdx.x;
    if (tid == 0) nz = 0;
    __syncthreads();
    int local = 0;
    for (int i = tid; i < BB * PP; i += blockDim.x) local |= pairs[2 * i + 1];
    if (local) atomicOr(&nz, 1);
    __syncthreads();
    bool is64 = (nz == 0);

    if (tid < PP) {
        int h, o;
        if (is64) {
            h = pairs[((long long)(b * PP + tid)) * 4 + 0];
            o = pairs[((long long)(b * PP + tid)) * 4 + 2];
        } else {
            h = pairs[((long long)(b * PP + tid)) * 2 + 0];
            o = pairs[((long long)(b * PP + tid)) * 2 + 1];
        }
        if (h == o) o = QQ;
        atomicMax(&lut[b * SLOTS + h * (QQ + 1) + o], tid);
    }
}

// ---------------------------------------------------------------------------
// Kernel 2 (unchanged, verified): one thread per (b,q): softmax max/argmax,
// boxes, masks.
__global__ void cls_box_mask_kernel(const float* __restrict__ logits,
                                    const float* __restrict__ boxes_in,
                                    const float* __restrict__ tsize,
                                    float* __restrict__ out) {
    int t = blockIdx.x * blockDim.x + threadIdx.x;
    if (t >= BB * QQ) return;
    int b = t / QQ;
    int q = t - b * QQ;

    const float* l = logits + (long long)t * CC;

    float m = -1e30f;
    float best = -1e30f;
    int am = 0;
    for (int c = 0; c < CC; ++c) {
        float x = l[c];
        m = fmaxf(m, x);
        if (c < CC - 1 && x > best) { best = x; am = c; }
    }
    float s = 0.0f;
    for (int c = 0; c < CC; ++c) {
        s += __expf(l[c] - m);
    }
    float score = __expf(best - m) / s;

    out[OFF_SCORES + t] = score;
    out[OFF_LABELS + t] = (float)am;

    float cx = boxes_in[4 * (long long)t + 0];
    float cy = boxes_in[4 * (long long)t + 1];
    float w  = boxes_in[4 * (long long)t + 2];
    float h  = boxes_in[4 * (long long)t + 3];
    float img_h = tsize[2 * b + 0];
    float img_w = tsize[2 * b + 1];
    out[OFF_BOXES + 4 * (long long)t + 0] = (cx - 0.5f * w) * img_w;
    out[OFF_BOXES + 4 * (long long)t + 1] = (cy - 0.5f * h) * img_h;
    out[OFF_BOXES + 4 * (long long)t + 2] = (cx + 0.5f * w) * img_w;
    out[OFF_BOXES + 4 * (long long)t + 3] = (cy + 0.5f * h) * img_h;

    out[OFF_HMASK + t] = (am == 1 && score > 0.0f) ? 1.0f : 0.0f;
    out[OFF_OMASK + (long long)b * (QQ + 1) + q] = (score > 0.0f) ? 1.0f : 0.0f;
    if (q == 0) out[OFF_OMASK + (long long)b * (QQ + 1) + QQ] = 1.0f;
}

// ---------------------------------------------------------------------------
// Kernel 3 (v2): fused single-pass writer. One block per (chunk, b); each
// thread holds its 16 LUT slots in registers (4x int4) and writes those slots
// for ALL 29 a-planes -> LUT read exactly once from HBM (11.5 MB total, vs
// 29x re-read in v1). Wave stores 64 consecutive float4 = 1 KB contiguous.
// Plain cached stores (NT measured slower in R1).
__global__ __launch_bounds__(256) void score_write_kernel(const int* __restrict__ lut,
                                                          const float* __restrict__ actions,
                                                          float* __restrict__ out) {
    int chunk = blockIdx.x;             // 0..22
    int b = blockIdx.y;                 // 0..31
    const int4* lb4 = (const int4*)(lut + b * SLOTS);
    const float* actb = actions + (long long)b * PP * AA;
    float* plane0 = out + OFF_SCORE + (long long)b * AA * SLOTS;

    int q0 = chunk * 1024 + threadIdx.x;   // this thread's quads: q0 + k*256

    int4 pi[4];
    bool valid[4];
    bool anyhit[4];
    #pragma unroll
    for (int k = 0; k < 4; ++k) {
        int q = q0 + k * 256;
        valid[k] = (q < SLOT4);
        pi[k] = valid[k] ? lb4[q] : make_int4(-1, -1, -1, -1);
        int mx = max(max(pi[k].x, pi[k].y), max(pi[k].z, pi[k].w));
        anyhit[k] = (mx >= 0);
    }

    for (int a = 0; a < AA; ++a) {
        f32x4* pl = (f32x4*)(plane0 + (long long)a * SLOTS);
        #pragma unroll
        for (int k = 0; k < 4; ++k) {
            if (!valid[k]) continue;
            f32x4 v = (f32x4)0.0f;
            if (anyhit[k]) {   // rare (~0.4% of quads); exec-masked for most waves
                if (pi[k].x >= 0) v.x = 1.0f / (1.0f + __expf(-actb[pi[k].x * AA + a]));
                if (pi[k].y >= 0) v.y = 1.0f / (1.0f + __expf(-actb[pi[k].y * AA + a]));
                if (pi[k].z >= 0) v.z = 1.0f / (1.0f + __expf(-actb[pi[k].z * AA + a]));
                if (pi[k].w >= 0) v.w = 1.0f / (1.0f + __expf(-actb[pi[k].w * AA + a]));
            }
            pl[q0 + k * 256] = v;
        }
    }
}

// ---------------------------------------------------------------------------
// Fallback path (workspace too small): R0 structure (memset + scatter).
__global__ void scatter_kernel(const int* __restrict__ pairs,
                               const float* __restrict__ actions,
                               float* __restrict__ out) {
    __shared__ int keys[PP];
    __shared__ int nz;
    int tid = threadIdx.x;
    if (tid == 0) nz = 0;
    __syncthreads();

    int local = 0;
    for (int i = tid; i < BB * PP; i += blockDim.x) local |= pairs[2 * i + 1];
    if (local) atomicOr(&nz, 1);
    __syncthreads();
    bool is64 = (nz == 0);

    int b = blockIdx.x;
    int p = tid;
    int h = -1, o = -1;
    if (p < PP) {
        if (is64) {
            h = pairs[((long long)(b * PP + p)) * 4 + 0];
            o = pairs[((long long)(b * PP + p)) * 4 + 2];
        } else {
            h = pairs[((long long)(b * PP + p)) * 2 + 0];
            o = pairs[((long long)(b * PP + p)) * 2 + 1];
        }
        if (h == o) o = QQ;
        keys[p] = h * (QQ + 1) + o;
    }
    __syncthreads();
    if (p >= PP) return;

    int k = keys[p];
    for (int p2 = p + 1; p2 < PP; ++p2) {
        if (keys[p2] == k) return;
    }

    const float* act = actions + (long long)(b * PP + p) * AA;
    long long base = OFF_SCORE + (long long)b * AA * QQ * (QQ + 1)
                   + (long long)h * (QQ + 1) + o;
    for (int a = 0; a < AA; ++a) {
        float x = act[a];
        float sg = 1.0f / (1.0f + __expf(-x));
        out[base + (long long)a * QQ * (QQ + 1)] = sg;
    }
}

extern "C" void kernel_launch(void* const* d_in, const int* in_sizes, int n_in,
                              void* d_out, int out_size, void* d_ws, size_t ws_size,
                              hipStream_t stream) {
    const float* logits   = (const float*)d_in[0]; // (B,Q,C)
    const float* boxes_in = (const float*)d_in[1]; // (B,Q,4)
    const float* actions  = (const float*)d_in[2]; // (B,P,A)
    const int*   pairs    = (const int*)d_in[3];   // (B,P,2) int
    const float* tsize    = (const float*)d_in[4]; // (B,2)
    float* out = (float*)d_out;

    int n = BB * QQ;
    if (d_ws != nullptr && ws_size >= LUT_BYTES) {
        int* lut = (int*)d_ws;
        lut_init_kernel<<<1024, 256, 0, stream>>>(lut);
        lut_scatter_kernel<<<BB, 320, 0, stream>>>(pairs, lut);
        cls_box_mask_kernel<<<(n + 255) / 256, 256, 0, stream>>>(logits, boxes_in, tsize, out);
        score_write_kernel<<<dim3(CHUNKS, BB), 256, 0, stream>>>(lut, actions, out);
    } else {
        // Fallback: R0 verified structure.
        hipMemsetAsync((char*)d_out + OFF_SCORE * sizeof(float), 0,
                       (size_t)SCORE_ELEMS * sizeof(float), stream);
        cls_box_mask_kernel<<<(n + 255) / 256, 256, 0, stream>>>(logits, boxes_in, tsize, out);
        scatter_kernel<<<BB, 320, 0, stream>>>(pairs, actions, out);
    }
}

// Round 6
// 412.163 us; speedup vs baseline: 1.0471x; 1.0471x over previous
//
#include <hip/hip_runtime.h>
#include <hip/hip_bf16.h>

// Problem constants (from reference): B,Q,C,P,A = 32,300,81,300,29
#define BB 32
#define QQ 300
#define CC 81
#define PP 300
#define AA 29

// Flat output layout (fp32 elements), concatenated in reference return order:
// scores(B,Q) | labels(B,Q) | boxes(B,Q,4) | score(B,A,Q,Q+1) | h_mask(B,Q) | o_mask(B,Q+1)
constexpr long long OFF_SCORES = 0;
constexpr long long OFF_LABELS = OFF_SCORES + (long long)BB * QQ;            // 9600
constexpr long long OFF_BOXES  = OFF_LABELS + (long long)BB * QQ;            // 19200
constexpr long long OFF_SCORE  = OFF_BOXES  + (long long)BB * QQ * 4;        // 57600
constexpr long long SCORE_ELEMS = (long long)BB * AA * QQ * (QQ + 1);        // 83,798,400
constexpr long long OFF_HMASK  = OFF_SCORE + SCORE_ELEMS;                    // 83,856,000
constexpr long long OFF_OMASK  = OFF_HMASK + (long long)BB * QQ;             // 83,865,600
// total = 83,875,232 elements

constexpr int SLOTS = QQ * (QQ + 1);          // 90,300 slots per (b,a) plane
constexpr int SCT_THREADS = 512;              // 1024 untested on this harness (R4/R5 infra fails); 512 is safe

// ---------------------------------------------------------------------------
// Session ledger (dur_us total / inferred controllable beyond ~318us harness tax):
//   R0 memset+scatter(320t)          396.7 / ~78   <- best structure
//   R1 NT-store fill + scatter       424.6 / ~106  (NT 16B stores: partial-line DRAM writes)
//   R2 LUT + fused writer (a-fast)   414.1 / ~95   (29x LUT re-read)
//   R3 LUT + fused writer (reg-LUT)  431.6 / ~113  (plane-strided stores, +2 launches)
//   R4/R5 memset+scatter(1024t)      infra failure x2 — resubmit with 512t scatter
// Conclusion: zero-fill at rocclr fill rate (~5.7 TB/s measured on the poison
// fill) + minimal scatter is optimal; fusion interleaves checks into the store
// stream and loses >=50% of fill BW. This file = R0 structure + faster scatter.
// ---------------------------------------------------------------------------

// One thread per (b,q): softmax max/argmax, boxes, masks. (verified since R0)
__global__ void cls_box_mask_kernel(const float* __restrict__ logits,
                                    const float* __restrict__ boxes_in,
                                    const float* __restrict__ tsize,
                                    float* __restrict__ out) {
    int t = blockIdx.x * blockDim.x + threadIdx.x;
    if (t >= BB * QQ) return;
    int b = t / QQ;
    int q = t - b * QQ;

    const float* l = logits + (long long)t * CC;

    // Pass 1: global max (all 81) + max/argmax over first 80 (first-index tie-break).
    float m = -1e30f;
    float best = -1e30f;
    int am = 0;
    for (int c = 0; c < CC; ++c) {
        float x = l[c];
        m = fmaxf(m, x);
        if (c < CC - 1 && x > best) { best = x; am = c; }
    }
    // Pass 2: softmax denominator (loads hit L1).
    float s = 0.0f;
    for (int c = 0; c < CC; ++c) {
        s += __expf(l[c] - m);
    }
    float score = __expf(best - m) / s;

    out[OFF_SCORES + t] = score;
    out[OFF_LABELS + t] = (float)am;

    // Boxes: cxcywh -> xyxy, scaled by [img_w, img_h, img_w, img_h].
    float cx = boxes_in[4 * (long long)t + 0];
    float cy = boxes_in[4 * (long long)t + 1];
    float w  = boxes_in[4 * (long long)t + 2];
    float h  = boxes_in[4 * (long long)t + 3];
    float img_h = tsize[2 * b + 0];
    float img_w = tsize[2 * b + 1];
    out[OFF_BOXES + 4 * (long long)t + 0] = (cx - 0.5f * w) * img_w;
    out[OFF_BOXES + 4 * (long long)t + 1] = (cy - 0.5f * h) * img_h;
    out[OFF_BOXES + 4 * (long long)t + 2] = (cx + 0.5f * w) * img_w;
    out[OFF_BOXES + 4 * (long long)t + 3] = (cy + 0.5f * h) * img_h;

    // Masks (threshold = 0.0).
    out[OFF_HMASK + t] = (am == 1 && score > 0.0f) ? 1.0f : 0.0f;
    out[OFF_OMASK + (long long)b * (QQ + 1) + q] = (score > 0.0f) ? 1.0f : 0.0f;
    if (q == 0) out[OFF_OMASK + (long long)b * (QQ + 1) + QQ] = 1.0f;
}

// ---------------------------------------------------------------------------
// Scatter v2b: one block per batch, 512 threads.
// Phase 1: threads 0..299 compute slot keys (o'=Q if h==o) into LDS and mark
//          the numpy-last-wins winner per duplicate key (later p wins).
// Phase 2: all 512 threads share the 300x29 = 8700 sigmoid+store work items
//          (~17 each) with consecutive lanes loading contiguous actions.
// Auto-detects int64 vs int32 storage of pred_rel_pairs: values in [0,300),
// so little-endian int64 => every odd 32-bit word is zero.
__global__ void scatter_kernel(const int* __restrict__ pairs,
                               const float* __restrict__ actions,
                               float* __restrict__ out) {
    __shared__ int s_key[PP];
    __shared__ int s_win[PP];
    __shared__ int nz;
    int tid = threadIdx.x;
    int b = blockIdx.x;
    if (tid == 0) nz = 0;
    __syncthreads();

    int local = 0;
    for (int i = tid; i < BB * PP; i += blockDim.x) local |= pairs[2 * i + 1];
    if (local) atomicOr(&nz, 1);
    __syncthreads();
    bool is64 = (nz == 0);

    if (tid < PP) {
        int h, o;
        if (is64) {
            h = pairs[((long long)(b * PP + tid)) * 4 + 0];
            o = pairs[((long long)(b * PP + tid)) * 4 + 2];
        } else {
            h = pairs[((long long)(b * PP + tid)) * 2 + 0];
            o = pairs[((long long)(b * PP + tid)) * 2 + 1];
        }
        if (h == o) o = QQ;
        s_key[tid] = h * (QQ + 1) + o;
    }
    __syncthreads();

    if (tid < PP) {
        int k = s_key[tid];
        int win = 1;
        for (int p2 = tid + 1; p2 < PP; ++p2) {
            if (s_key[p2] == k) { win = 0; break; }  // a later pair wins the slot
        }
        s_win[tid] = win;
    }
    __syncthreads();

    const float* actb = actions + (long long)b * PP * AA;
    float* scoreb = out + OFF_SCORE + (long long)b * AA * SLOTS;
    for (int i = tid; i < PP * AA; i += SCT_THREADS) {
        int p = i / AA;
        int a = i - p * AA;          // consecutive lanes: contiguous actions loads
        if (!s_win[p]) continue;
        float x = actb[p * AA + a];
        float sg = 1.0f / (1.0f + __expf(-x));
        scoreb[(long long)a * SLOTS + s_key[p]] = sg;
    }
}

extern "C" void kernel_launch(void* const* d_in, const int* in_sizes, int n_in,
                              void* d_out, int out_size, void* d_ws, size_t ws_size,
                              hipStream_t stream) {
    const float* logits   = (const float*)d_in[0]; // (B,Q,C)
    const float* boxes_in = (const float*)d_in[1]; // (B,Q,4)
    const float* actions  = (const float*)d_in[2]; // (B,P,A)
    const int*   pairs    = (const int*)d_in[3];   // (B,P,2) int
    const float* tsize    = (const float*)d_in[4]; // (B,2)
    float* out = (float*)d_out;

    // Zero the score region via the rocclr fill path: measured ~5.7 TB/s
    // (the fastest observed way to write this buffer; our NT/custom fills
    // and fused writers all measured slower, see ledger above).
    hipMemsetAsync((char*)d_out + OFF_SCORE * sizeof(float), 0,
                   (size_t)SCORE_ELEMS * sizeof(float), stream);

    int n = BB * QQ;
    cls_box_mask_kernel<<<(n + 255) / 256, 256, 0, stream>>>(logits, boxes_in, tsize, out);
    scatter_kernel<<<BB, SCT_THREADS, 0, stream>>>(pairs, actions, out);
}